// Round 1
// baseline (621.428 us; speedup 1.0000x reference)
//
#include <hip/hip_runtime.h>

// TAGConv: N=50000 nodes, E=800000 edges, F=64, OUT=64, K=3 hops.
// h0=x; h_{k+1}[i] = sum_{e:(row=i)} val[e]*h_k[col[e]];
// out = concat(h0..h3) @ W + b, computed as out = b + sum_s h_s @ W_s.

#define F 64
#define OUT 64

// One wave per edge, lane = feature. Coalesced gather + coalesced atomic scatter.
__global__ __launch_bounds__(256) void spmm_atomic(
    const int* __restrict__ row, const int* __restrict__ col,
    const float* __restrict__ val, const float* __restrict__ hin,
    float* __restrict__ hout, int E) {
  int e = blockIdx.x * 4 + (threadIdx.x >> 6);
  if (e >= E) return;
  int lane = threadIdx.x & 63;
  int r = row[e];
  int c = col[e];
  float v = val[e];
  atomicAdd(&hout[(size_t)r * F + lane], v * hin[(size_t)c * F + lane]);
}

// out[n][o] (+)= h[n][0:64] @ Wc[0:64][o]  (+ b[o] when init).
// Block: 64 nodes x 64 outputs; 256 threads; thread = (node, 16 outputs).
__global__ __launch_bounds__(256) void gemm_stage(
    const float* __restrict__ h, const float* __restrict__ Wc,
    const float* __restrict__ b, float* __restrict__ out,
    int N, int init) {
  __shared__ float Ws[64 * 64];      // W chunk, row-major [k][o]
  __shared__ float Hs[64 * 65];      // h tile, +1 pad kills stride-64 conflicts

  int node0 = blockIdx.x * 64;
  for (int i = threadIdx.x; i < 64 * 64; i += 256) {
    Ws[i] = Wc[i];
    int r = i >> 6, c = i & 63;
    int n = node0 + r;
    Hs[r * 65 + c] = (n < N) ? h[(size_t)n * F + c] : 0.f;
  }
  __syncthreads();

  int nl = threadIdx.x >> 2;
  int node = node0 + nl;
  if (node >= N) return;
  int og = (threadIdx.x & 3) << 4;   // 16 consecutive outputs

  float acc[16];
  if (init) {
#pragma unroll
    for (int j = 0; j < 16; ++j) acc[j] = b[og + j];
  } else {
    const float4* o4 = (const float4*)&out[(size_t)node * OUT + og];
#pragma unroll
    for (int j = 0; j < 4; ++j) {
      float4 t = o4[j];
      acc[4 * j] = t.x; acc[4 * j + 1] = t.y; acc[4 * j + 2] = t.z; acc[4 * j + 3] = t.w;
    }
  }

#pragma unroll 4
  for (int k = 0; k < 64; ++k) {
    float hv = Hs[nl * 65 + k];
    const float4* w4 = (const float4*)&Ws[k * 64 + og];
#pragma unroll
    for (int j = 0; j < 4; ++j) {
      float4 w = w4[j];
      acc[4 * j]     = fmaf(hv, w.x, acc[4 * j]);
      acc[4 * j + 1] = fmaf(hv, w.y, acc[4 * j + 1]);
      acc[4 * j + 2] = fmaf(hv, w.z, acc[4 * j + 2]);
      acc[4 * j + 3] = fmaf(hv, w.w, acc[4 * j + 3]);
    }
  }

  float4* o4 = (float4*)&out[(size_t)node * OUT + og];
#pragma unroll
  for (int j = 0; j < 4; ++j)
    o4[j] = make_float4(acc[4 * j], acc[4 * j + 1], acc[4 * j + 2], acc[4 * j + 3]);
}

extern "C" void kernel_launch(void* const* d_in, const int* in_sizes, int n_in,
                              void* d_out, int out_size, void* d_ws, size_t ws_size,
                              hipStream_t stream) {
  const float* x    = (const float*)d_in[0];
  const int*   erow = (const int*)d_in[1];
  const int*   ecol = (const int*)d_in[2];
  const float* eval = (const float*)d_in[3];
  const float* W    = (const float*)d_in[4];
  const float* b    = (const float*)d_in[5];
  float* out = (float*)d_out;

  int N = in_sizes[0] / F;
  int E = in_sizes[1];
  size_t SZ = (size_t)N * F * sizeof(float);

  float* hA = (float*)d_ws;                    // ping
  float* hB = (float*)((char*)d_ws + SZ);      // pong

  int spmmGrid = (E + 3) / 4;
  int gemmGrid = (N + 63) / 64;

  // h1 = spmm(x)
  hipMemsetAsync(hA, 0, SZ, stream);
  spmm_atomic<<<spmmGrid, 256, 0, stream>>>(erow, ecol, eval, x, hA, E);
  // out = b + x @ W0
  gemm_stage<<<gemmGrid, 256, 0, stream>>>(x, W + 0 * 64 * 64, b, out, N, 1);
  // out += h1 @ W1
  gemm_stage<<<gemmGrid, 256, 0, stream>>>(hA, W + 1 * 64 * 64, b, out, N, 0);

  // h2 = spmm(h1)
  hipMemsetAsync(hB, 0, SZ, stream);
  spmm_atomic<<<spmmGrid, 256, 0, stream>>>(erow, ecol, eval, hA, hB, E);
  // out += h2 @ W2
  gemm_stage<<<gemmGrid, 256, 0, stream>>>(hB, W + 2 * 64 * 64, b, out, N, 0);

  // h3 = spmm(h2)
  hipMemsetAsync(hA, 0, SZ, stream);
  spmm_atomic<<<spmmGrid, 256, 0, stream>>>(erow, ecol, eval, hB, hA, E);
  // out += h3 @ W3
  gemm_stage<<<gemmGrid, 256, 0, stream>>>(hA, W + 3 * 64 * 64, b, out, N, 0);
}

// Round 2
// 396.052 us; speedup vs baseline: 1.5691x; 1.5691x over previous
//
#include <hip/hip_runtime.h>

// TAGConv: N=50000 nodes, E=800000 edges, F=64, OUT=64, K=3 hops.
// Round 2: replace atomic-scatter SpMM with on-device CSR build (counting sort)
// + gather-only SpMM (register accumulate, one store per row).

#define F 64
#define OUT 64

__global__ __launch_bounds__(256) void count_rows(
    const int* __restrict__ row, int* __restrict__ counts, int E) {
  int e = blockIdx.x * 256 + threadIdx.x;
  if (e < E) atomicAdd(&counts[row[e]], 1);
}

// Single-block hierarchical exclusive scan over counts[0..N) -> offsets[0..N],
// duplicated into cursor[0..N) for the scatter pass.
__global__ __launch_bounds__(1024) void scan_offsets(
    const int* __restrict__ counts, int* __restrict__ offsets,
    int* __restrict__ cursor, int N) {
  __shared__ int s[1024];
  int t = threadIdx.x;
  int chunk = (N + 1023) / 1024;
  int b = t * chunk;
  int e = min(b + chunk, N);
  int sum = 0;
  for (int i = b; i < e; ++i) sum += counts[i];
  s[t] = sum;
  __syncthreads();
  // Hillis-Steele inclusive scan over the 1024 chunk sums.
  for (int d = 1; d < 1024; d <<= 1) {
    int v = (t >= d) ? s[t - d] : 0;
    __syncthreads();
    s[t] += v;
    __syncthreads();
  }
  int run = (t == 0) ? 0 : s[t - 1];
  for (int i = b; i < e; ++i) {
    offsets[i] = run;
    cursor[i] = run;
    run += counts[i];
  }
  if (b < N && e == N) offsets[N] = run;  // total
}

__global__ __launch_bounds__(256) void scatter_edges(
    const int* __restrict__ row, const int* __restrict__ col,
    const float* __restrict__ val, int* __restrict__ cursor,
    int* __restrict__ ccol, float* __restrict__ cval, int E) {
  int e = blockIdx.x * 256 + threadIdx.x;
  if (e < E) {
    int r = row[e];
    int p = atomicAdd(&cursor[r], 1);
    ccol[p] = col[e];
    cval[p] = val[e];
  }
}

// One wave per row, lane = feature. 4-way unrolled gather, register acc,
// single coalesced 256B store per row. No atomics, no pre-zeroing needed.
__global__ __launch_bounds__(256) void spmm_csr(
    const int* __restrict__ off, const int* __restrict__ ccol,
    const float* __restrict__ cval, const float* __restrict__ hin,
    float* __restrict__ hout, int N) {
  int r = blockIdx.x * 4 + (threadIdx.x >> 6);
  if (r >= N) return;
  int lane = threadIdx.x & 63;
  int i = off[r], end = off[r + 1];
  float acc = 0.f;
  for (; i + 4 <= end; i += 4) {
    int c0 = ccol[i], c1 = ccol[i + 1], c2 = ccol[i + 2], c3 = ccol[i + 3];
    float v0 = cval[i], v1 = cval[i + 1], v2 = cval[i + 2], v3 = cval[i + 3];
    float a0 = hin[(size_t)c0 * F + lane];
    float a1 = hin[(size_t)c1 * F + lane];
    float a2 = hin[(size_t)c2 * F + lane];
    float a3 = hin[(size_t)c3 * F + lane];
    acc = fmaf(v0, a0, acc);
    acc = fmaf(v1, a1, acc);
    acc = fmaf(v2, a2, acc);
    acc = fmaf(v3, a3, acc);
  }
  for (; i < end; ++i)
    acc = fmaf(cval[i], hin[(size_t)ccol[i] * F + lane], acc);
  hout[(size_t)r * F + lane] = acc;
}

// out[n][o] (+)= h[n][0:64] @ Wc[0:64][o]  (+ b[o] when init).
__global__ __launch_bounds__(256) void gemm_stage(
    const float* __restrict__ h, const float* __restrict__ Wc,
    const float* __restrict__ b, float* __restrict__ out,
    int N, int init) {
  __shared__ float Ws[64 * 64];
  __shared__ float Hs[64 * 65];  // +1 pad kills stride-64 conflicts

  int node0 = blockIdx.x * 64;
  for (int i = threadIdx.x; i < 64 * 64; i += 256) {
    Ws[i] = Wc[i];
    int r = i >> 6, c = i & 63;
    int n = node0 + r;
    Hs[r * 65 + c] = (n < N) ? h[(size_t)n * F + c] : 0.f;
  }
  __syncthreads();

  int nl = threadIdx.x >> 2;
  int node = node0 + nl;
  if (node >= N) return;
  int og = (threadIdx.x & 3) << 4;

  float acc[16];
  if (init) {
#pragma unroll
    for (int j = 0; j < 16; ++j) acc[j] = b[og + j];
  } else {
    const float4* o4 = (const float4*)&out[(size_t)node * OUT + og];
#pragma unroll
    for (int j = 0; j < 4; ++j) {
      float4 t = o4[j];
      acc[4 * j] = t.x; acc[4 * j + 1] = t.y; acc[4 * j + 2] = t.z; acc[4 * j + 3] = t.w;
    }
  }

#pragma unroll 4
  for (int k = 0; k < 64; ++k) {
    float hv = Hs[nl * 65 + k];
    const float4* w4 = (const float4*)&Ws[k * 64 + og];
#pragma unroll
    for (int j = 0; j < 4; ++j) {
      float4 w = w4[j];
      acc[4 * j]     = fmaf(hv, w.x, acc[4 * j]);
      acc[4 * j + 1] = fmaf(hv, w.y, acc[4 * j + 1]);
      acc[4 * j + 2] = fmaf(hv, w.z, acc[4 * j + 2]);
      acc[4 * j + 3] = fmaf(hv, w.w, acc[4 * j + 3]);
    }
  }

  float4* o4 = (float4*)&out[(size_t)node * OUT + og];
#pragma unroll
  for (int j = 0; j < 4; ++j)
    o4[j] = make_float4(acc[4 * j], acc[4 * j + 1], acc[4 * j + 2], acc[4 * j + 3]);
}

extern "C" void kernel_launch(void* const* d_in, const int* in_sizes, int n_in,
                              void* d_out, int out_size, void* d_ws, size_t ws_size,
                              hipStream_t stream) {
  const float* x    = (const float*)d_in[0];
  const int*   erow = (const int*)d_in[1];
  const int*   ecol = (const int*)d_in[2];
  const float* eval = (const float*)d_in[3];
  const float* W    = (const float*)d_in[4];
  const float* b    = (const float*)d_in[5];
  float* out = (float*)d_out;

  int N = in_sizes[0] / F;
  int E = in_sizes[1];
  size_t SZ = (size_t)N * F * sizeof(float);

  // ws layout
  char* p = (char*)d_ws;
  float* hA     = (float*)p;            p += SZ;                        // 12.8 MB
  float* hB     = (float*)p;            p += SZ;                        // 12.8 MB
  int*   counts = (int*)p;              p += (size_t)N * sizeof(int);
  int*   offs   = (int*)p;              p += (size_t)(N + 1) * sizeof(int);
  int*   cursor = (int*)p;              p += (size_t)N * sizeof(int);
  int*   ccol   = (int*)p;              p += (size_t)E * sizeof(int);
  float* cval   = (float*)p;            p += (size_t)E * sizeof(float);

  int egrid = (E + 255) / 256;
  int sgrid = (N + 3) / 4;
  int ggrid = (N + 63) / 64;

  // --- CSR build ---
  hipMemsetAsync(counts, 0, (size_t)N * sizeof(int), stream);
  count_rows<<<egrid, 256, 0, stream>>>(erow, counts, E);
  scan_offsets<<<1, 1024, 0, stream>>>(counts, offs, cursor, N);
  scatter_edges<<<egrid, 256, 0, stream>>>(erow, ecol, eval, cursor, ccol, cval, E);

  // --- propagation + staged GEMM ---
  // h1 = A x
  spmm_csr<<<sgrid, 256, 0, stream>>>(offs, ccol, cval, x, hA, N);
  gemm_stage<<<ggrid, 256, 0, stream>>>(x, W + 0 * 64 * 64, b, out, N, 1);
  gemm_stage<<<ggrid, 256, 0, stream>>>(hA, W + 1 * 64 * 64, b, out, N, 0);

  // h2 = A h1
  spmm_csr<<<sgrid, 256, 0, stream>>>(offs, ccol, cval, hA, hB, N);
  gemm_stage<<<ggrid, 256, 0, stream>>>(hB, W + 2 * 64 * 64, b, out, N, 0);

  // h3 = A h2
  spmm_csr<<<sgrid, 256, 0, stream>>>(offs, ccol, cval, hB, hA, N);
  gemm_stage<<<ggrid, 256, 0, stream>>>(hA, W + 3 * 64 * 64, b, out, N, 0);
}

// Round 3
// 287.433 us; speedup vs baseline: 2.1620x; 1.3779x over previous
//
#include <hip/hip_runtime.h>

// TAGConv: N=50000 nodes, E=800000 edges, F=64, OUT=64, K=3 hops.
// Round 3: multi-block scan (kills the 110us single-block scan) + fused GEMM.

#define F 64
#define OUT 64
#define SCAN_ELEMS 1024  // elements scanned per block (4 per thread)

__global__ __launch_bounds__(256) void count_rows(
    const int* __restrict__ row, int* __restrict__ counts, int E) {
  int e = blockIdx.x * 256 + threadIdx.x;
  if (e < E) atomicAdd(&counts[row[e]], 1);
}

// Per-block local exclusive scan of counts -> offsets, block totals -> blockSums.
__global__ __launch_bounds__(256) void block_scan(
    const int* __restrict__ counts, int* __restrict__ offsets,
    int* __restrict__ blockSums, int N) {
  __shared__ int s[256];
  int t = threadIdx.x;
  int base = blockIdx.x * SCAN_ELEMS + t * 4;
  int v0 = 0, v1 = 0, v2 = 0, v3 = 0;
  if (base + 3 < N) {
    int4 c = *(const int4*)&counts[base];
    v0 = c.x; v1 = c.y; v2 = c.z; v3 = c.w;
  } else {
    if (base < N)     v0 = counts[base];
    if (base + 1 < N) v1 = counts[base + 1];
    if (base + 2 < N) v2 = counts[base + 2];
  }
  s[t] = v0 + v1 + v2 + v3;
  __syncthreads();
  for (int d = 1; d < 256; d <<= 1) {
    int x = (t >= d) ? s[t - d] : 0;
    __syncthreads();
    s[t] += x;
    __syncthreads();
  }
  int ex = (t == 0) ? 0 : s[t - 1];
  if (t == 255) blockSums[blockIdx.x] = s[255];
  int o0 = ex, o1 = o0 + v0, o2 = o1 + v1, o3 = o2 + v2;
  if (base + 3 < N) {
    *(int4*)&offsets[base] = make_int4(o0, o1, o2, o3);
  } else {
    if (base < N)     offsets[base]     = o0;
    if (base + 1 < N) offsets[base + 1] = o1;
    if (base + 2 < N) offsets[base + 2] = o2;
  }
}

// Exclusive scan of blockSums in place. One wave handles nb<=64; serial fallback.
__global__ __launch_bounds__(64) void scan_sums(int* __restrict__ blockSums, int nb) {
  int lane = threadIdx.x;
  if (nb <= 64) {
    int v = (lane < nb) ? blockSums[lane] : 0;
    int incl = v;
    for (int d = 1; d < 64; d <<= 1) {
      int u = __shfl_up(incl, d, 64);
      if (lane >= d) incl += u;
    }
    if (lane < nb) blockSums[lane] = incl - v;
  } else if (lane == 0) {
    int run = 0;
    for (int i = 0; i < nb; ++i) { int c = blockSums[i]; blockSums[i] = run; run += c; }
  }
}

__global__ __launch_bounds__(256) void add_offsets(
    int* __restrict__ offsets, const int* __restrict__ blockSums,
    int* __restrict__ cursor, int N, int E) {
  int i = blockIdx.x * 256 + threadIdx.x;
  if (i < N) {
    int o = offsets[i] + blockSums[i >> 10];
    offsets[i] = o;
    cursor[i] = o;
  }
  if (i == 0) offsets[N] = E;
}

__global__ __launch_bounds__(256) void scatter_edges(
    const int* __restrict__ row, const int* __restrict__ col,
    const float* __restrict__ val, int* __restrict__ cursor,
    int* __restrict__ ccol, float* __restrict__ cval, int E) {
  int e = blockIdx.x * 256 + threadIdx.x;
  if (e < E) {
    int r = row[e];
    int p = atomicAdd(&cursor[r], 1);
    ccol[p] = col[e];
    cval[p] = val[e];
  }
}

// One wave per row, lane = feature. Gather-only, register acc, one store/row.
__global__ __launch_bounds__(256) void spmm_csr(
    const int* __restrict__ off, const int* __restrict__ ccol,
    const float* __restrict__ cval, const float* __restrict__ hin,
    float* __restrict__ hout, int N) {
  int r = blockIdx.x * 4 + (threadIdx.x >> 6);
  if (r >= N) return;
  int lane = threadIdx.x & 63;
  int i = off[r], end = off[r + 1];
  float acc = 0.f;
  for (; i + 4 <= end; i += 4) {
    int c0 = ccol[i], c1 = ccol[i + 1], c2 = ccol[i + 2], c3 = ccol[i + 3];
    float v0 = cval[i], v1 = cval[i + 1], v2 = cval[i + 2], v3 = cval[i + 3];
    float a0 = hin[(size_t)c0 * F + lane];
    float a1 = hin[(size_t)c1 * F + lane];
    float a2 = hin[(size_t)c2 * F + lane];
    float a3 = hin[(size_t)c3 * F + lane];
    acc = fmaf(v0, a0, acc);
    acc = fmaf(v1, a1, acc);
    acc = fmaf(v2, a2, acc);
    acc = fmaf(v3, a3, acc);
  }
  for (; i < end; ++i)
    acc = fmaf(cval[i], hin[(size_t)ccol[i] * F + lane], acc);
  hout[(size_t)r * F + lane] = acc;
}

// out = b + h0@W0 + h1@W1 + h2@W2 (single pass over out).
__global__ __launch_bounds__(256) void gemm_fused3(
    const float* __restrict__ h0, const float* __restrict__ h1,
    const float* __restrict__ h2, const float* __restrict__ W,
    const float* __restrict__ b, float* __restrict__ out, int N) {
  __shared__ float Ws[64 * 64];
  __shared__ float Hs[64 * 65];
  const float* hs[3] = {h0, h1, h2};

  int node0 = blockIdx.x * 64;
  int nl = threadIdx.x >> 2;
  int og = (threadIdx.x & 3) << 4;

  float acc[16];
#pragma unroll
  for (int j = 0; j < 16; ++j) acc[j] = b[og + j];

  for (int s = 0; s < 3; ++s) {
    const float* h = hs[s];
    const float* Wc = W + s * 64 * 64;
    __syncthreads();  // protect LDS from previous stage's readers
    for (int i = threadIdx.x; i < 64 * 64; i += 256) {
      Ws[i] = Wc[i];
      int r = i >> 6, c = i & 63;
      int n = node0 + r;
      Hs[r * 65 + c] = (n < N) ? h[(size_t)n * F + c] : 0.f;
    }
    __syncthreads();
#pragma unroll 4
    for (int k = 0; k < 64; ++k) {
      float hv = Hs[nl * 65 + k];
      const float4* w4 = (const float4*)&Ws[k * 64 + og];
#pragma unroll
      for (int j = 0; j < 4; ++j) {
        float4 w = w4[j];
        acc[4 * j]     = fmaf(hv, w.x, acc[4 * j]);
        acc[4 * j + 1] = fmaf(hv, w.y, acc[4 * j + 1]);
        acc[4 * j + 2] = fmaf(hv, w.z, acc[4 * j + 2]);
        acc[4 * j + 3] = fmaf(hv, w.w, acc[4 * j + 3]);
      }
    }
  }

  int node = node0 + nl;
  if (node < N) {
    float4* o4 = (float4*)&out[(size_t)node * OUT + og];
#pragma unroll
    for (int j = 0; j < 4; ++j)
      o4[j] = make_float4(acc[4 * j], acc[4 * j + 1], acc[4 * j + 2], acc[4 * j + 3]);
  }
}

// out += h@Wc (single stage, for W3).
__global__ __launch_bounds__(256) void gemm_stage(
    const float* __restrict__ h, const float* __restrict__ Wc,
    float* __restrict__ out, int N) {
  __shared__ float Ws[64 * 64];
  __shared__ float Hs[64 * 65];

  int node0 = blockIdx.x * 64;
  for (int i = threadIdx.x; i < 64 * 64; i += 256) {
    Ws[i] = Wc[i];
    int r = i >> 6, c = i & 63;
    int n = node0 + r;
    Hs[r * 65 + c] = (n < N) ? h[(size_t)n * F + c] : 0.f;
  }
  __syncthreads();

  int nl = threadIdx.x >> 2;
  int node = node0 + nl;
  if (node >= N) return;
  int og = (threadIdx.x & 3) << 4;

  float acc[16];
  const float4* i4 = (const float4*)&out[(size_t)node * OUT + og];
#pragma unroll
  for (int j = 0; j < 4; ++j) {
    float4 t = i4[j];
    acc[4 * j] = t.x; acc[4 * j + 1] = t.y; acc[4 * j + 2] = t.z; acc[4 * j + 3] = t.w;
  }

#pragma unroll 4
  for (int k = 0; k < 64; ++k) {
    float hv = Hs[nl * 65 + k];
    const float4* w4 = (const float4*)&Ws[k * 64 + og];
#pragma unroll
    for (int j = 0; j < 4; ++j) {
      float4 w = w4[j];
      acc[4 * j]     = fmaf(hv, w.x, acc[4 * j]);
      acc[4 * j + 1] = fmaf(hv, w.y, acc[4 * j + 1]);
      acc[4 * j + 2] = fmaf(hv, w.z, acc[4 * j + 2]);
      acc[4 * j + 3] = fmaf(hv, w.w, acc[4 * j + 3]);
    }
  }

  float4* o4 = (float4*)&out[(size_t)node * OUT + og];
#pragma unroll
  for (int j = 0; j < 4; ++j)
    o4[j] = make_float4(acc[4 * j], acc[4 * j + 1], acc[4 * j + 2], acc[4 * j + 3]);
}

extern "C" void kernel_launch(void* const* d_in, const int* in_sizes, int n_in,
                              void* d_out, int out_size, void* d_ws, size_t ws_size,
                              hipStream_t stream) {
  const float* x    = (const float*)d_in[0];
  const int*   erow = (const int*)d_in[1];
  const int*   ecol = (const int*)d_in[2];
  const float* eval = (const float*)d_in[3];
  const float* W    = (const float*)d_in[4];
  const float* b    = (const float*)d_in[5];
  float* out = (float*)d_out;

  int N = in_sizes[0] / F;
  int E = in_sizes[1];
  size_t SZ = (size_t)N * F * sizeof(float);
  int nScanBlocks = (N + SCAN_ELEMS - 1) / SCAN_ELEMS;

  // ws layout
  char* p = (char*)d_ws;
  float* hA       = (float*)p; p += SZ;
  float* hB       = (float*)p; p += SZ;
  int*   counts   = (int*)p;   p += (size_t)N * sizeof(int);
  int*   offs     = (int*)p;   p += (size_t)(N + 1) * sizeof(int);
  int*   cursor   = (int*)p;   p += (size_t)N * sizeof(int);
  int*   bsums    = (int*)p;   p += (size_t)nScanBlocks * sizeof(int);
  int*   ccol     = (int*)p;   p += (size_t)E * sizeof(int);
  float* cval     = (float*)p; p += (size_t)E * sizeof(float);

  int egrid = (E + 255) / 256;
  int sgrid = (N + 3) / 4;
  int ggrid = (N + 63) / 64;

  // --- CSR build ---
  hipMemsetAsync(counts, 0, (size_t)N * sizeof(int), stream);
  count_rows<<<egrid, 256, 0, stream>>>(erow, counts, E);
  block_scan<<<nScanBlocks, 256, 0, stream>>>(counts, offs, bsums, N);
  scan_sums<<<1, 64, 0, stream>>>(bsums, nScanBlocks);
  add_offsets<<<(N + 255) / 256, 256, 0, stream>>>(offs, bsums, cursor, N, E);
  scatter_edges<<<egrid, 256, 0, stream>>>(erow, ecol, eval, cursor, ccol, cval, E);

  // --- propagation ---
  spmm_csr<<<sgrid, 256, 0, stream>>>(offs, ccol, cval, x, hA, N);   // h1
  spmm_csr<<<sgrid, 256, 0, stream>>>(offs, ccol, cval, hA, hB, N);  // h2

  // out = b + x@W0 + h1@W1 + h2@W2
  gemm_fused3<<<ggrid, 256, 0, stream>>>(x, hA, hB, W, b, out, N);

  // h3 = A h2 (reuse hA), out += h3@W3
  spmm_csr<<<sgrid, 256, 0, stream>>>(offs, ccol, cval, hB, hA, N);
  gemm_stage<<<ggrid, 256, 0, stream>>>(hA, W + 3 * 64 * 64, out, N);
}

// Round 4
// 271.585 us; speedup vs baseline: 2.2882x; 1.0584x over previous
//
#include <hip/hip_runtime.h>

// TAGConv: N=50000, E=800000, F=64, OUT=64, K=3.
// Round 4: interleaved (col,val) edge records (halve scatter write-amp),
// spmm3 -> d_out as scratch, single fused 4-stage GEMM.

#define F 64
#define OUT 64
#define SCAN_ELEMS 1024

__global__ __launch_bounds__(256) void count_rows(
    const int* __restrict__ row, int* __restrict__ counts, int E) {
  int e = blockIdx.x * 256 + threadIdx.x;
  if (e < E) atomicAdd(&counts[row[e]], 1);
}

__global__ __launch_bounds__(256) void block_scan(
    const int* __restrict__ counts, int* __restrict__ offsets,
    int* __restrict__ blockSums, int N) {
  __shared__ int s[256];
  int t = threadIdx.x;
  int base = blockIdx.x * SCAN_ELEMS + t * 4;
  int v0 = 0, v1 = 0, v2 = 0, v3 = 0;
  if (base + 3 < N) {
    int4 c = *(const int4*)&counts[base];
    v0 = c.x; v1 = c.y; v2 = c.z; v3 = c.w;
  } else {
    if (base < N)     v0 = counts[base];
    if (base + 1 < N) v1 = counts[base + 1];
    if (base + 2 < N) v2 = counts[base + 2];
  }
  s[t] = v0 + v1 + v2 + v3;
  __syncthreads();
  for (int d = 1; d < 256; d <<= 1) {
    int x = (t >= d) ? s[t - d] : 0;
    __syncthreads();
    s[t] += x;
    __syncthreads();
  }
  int ex = (t == 0) ? 0 : s[t - 1];
  if (t == 255) blockSums[blockIdx.x] = s[255];
  int o0 = ex, o1 = o0 + v0, o2 = o1 + v1, o3 = o2 + v2;
  if (base + 3 < N) {
    *(int4*)&offsets[base] = make_int4(o0, o1, o2, o3);
  } else {
    if (base < N)     offsets[base]     = o0;
    if (base + 1 < N) offsets[base + 1] = o1;
    if (base + 2 < N) offsets[base + 2] = o2;
  }
}

__global__ __launch_bounds__(64) void scan_sums(int* __restrict__ blockSums, int nb) {
  int lane = threadIdx.x;
  if (nb <= 64) {
    int v = (lane < nb) ? blockSums[lane] : 0;
    int incl = v;
    for (int d = 1; d < 64; d <<= 1) {
      int u = __shfl_up(incl, d, 64);
      if (lane >= d) incl += u;
    }
    if (lane < nb) blockSums[lane] = incl - v;
  } else if (lane == 0) {
    int run = 0;
    for (int i = 0; i < nb; ++i) { int c = blockSums[i]; blockSums[i] = run; run += c; }
  }
}

__global__ __launch_bounds__(256) void add_offsets(
    int* __restrict__ offsets, const int* __restrict__ blockSums,
    int* __restrict__ cursor, int N, int E) {
  int i = blockIdx.x * 256 + threadIdx.x;
  if (i < N) {
    int o = offsets[i] + blockSums[i >> 10];
    offsets[i] = o;
    cursor[i] = o;
  }
  if (i == 0) offsets[N] = E;
}

// One 8B interleaved record per edge: (col as int bits, val).
__global__ __launch_bounds__(256) void scatter_edges(
    const int* __restrict__ row, const int* __restrict__ col,
    const float* __restrict__ val, int* __restrict__ cursor,
    float2* __restrict__ recs, int E) {
  int e = blockIdx.x * 256 + threadIdx.x;
  if (e < E) {
    int r = row[e];
    int p = atomicAdd(&cursor[r], 1);
    recs[p] = make_float2(__int_as_float(col[e]), val[e]);
  }
}

// One wave per row, lane = feature. Record stream = one 8B load/edge.
__global__ __launch_bounds__(256) void spmm_rec(
    const int* __restrict__ off, const float2* __restrict__ recs,
    const float* __restrict__ hin, float* __restrict__ hout, int N) {
  int r = blockIdx.x * 4 + (threadIdx.x >> 6);
  if (r >= N) return;
  int lane = threadIdx.x & 63;
  int i = off[r], end = off[r + 1];
  float acc = 0.f;
  for (; i + 4 <= end; i += 4) {
    float2 e0 = recs[i], e1 = recs[i + 1], e2 = recs[i + 2], e3 = recs[i + 3];
    float a0 = hin[(size_t)__float_as_int(e0.x) * F + lane];
    float a1 = hin[(size_t)__float_as_int(e1.x) * F + lane];
    float a2 = hin[(size_t)__float_as_int(e2.x) * F + lane];
    float a3 = hin[(size_t)__float_as_int(e3.x) * F + lane];
    acc = fmaf(e0.y, a0, acc);
    acc = fmaf(e1.y, a1, acc);
    acc = fmaf(e2.y, a2, acc);
    acc = fmaf(e3.y, a3, acc);
  }
  for (; i < end; ++i) {
    float2 e0 = recs[i];
    acc = fmaf(e0.y, hin[(size_t)__float_as_int(e0.x) * F + lane], acc);
  }
  hout[(size_t)r * F + lane] = acc;
}

// out = b + h0@W0 + h1@W1 + h2@W2 + h3@W3, where h3 lives in `out` itself.
// Each block loads its own out-tile into LDS (stage 3) before overwriting.
__global__ __launch_bounds__(256) void gemm_fused4(
    const float* __restrict__ h0, const float* __restrict__ h1,
    const float* __restrict__ h2, const float* __restrict__ W,
    const float* __restrict__ b, float* __restrict__ out, int N) {
  __shared__ float Ws[64 * 64];
  __shared__ float Hs[64 * 65];
  const float* hs[4] = {h0, h1, h2, out};

  int node0 = blockIdx.x * 64;
  int nl = threadIdx.x >> 2;
  int og = (threadIdx.x & 3) << 4;

  float acc[16];
#pragma unroll
  for (int j = 0; j < 16; ++j) acc[j] = b[og + j];

  for (int s = 0; s < 4; ++s) {
    const float* h = hs[s];
    const float* Wc = W + s * 64 * 64;
    __syncthreads();
    for (int i = threadIdx.x; i < 64 * 64; i += 256) {
      Ws[i] = Wc[i];
      int r = i >> 6, c = i & 63;
      int n = node0 + r;
      Hs[r * 65 + c] = (n < N) ? h[(size_t)n * F + c] : 0.f;
    }
    __syncthreads();
#pragma unroll 4
    for (int k = 0; k < 64; ++k) {
      float hv = Hs[nl * 65 + k];
      const float4* w4 = (const float4*)&Ws[k * 64 + og];
#pragma unroll
      for (int j = 0; j < 4; ++j) {
        float4 w = w4[j];
        acc[4 * j]     = fmaf(hv, w.x, acc[4 * j]);
        acc[4 * j + 1] = fmaf(hv, w.y, acc[4 * j + 1]);
        acc[4 * j + 2] = fmaf(hv, w.z, acc[4 * j + 2]);
        acc[4 * j + 3] = fmaf(hv, w.w, acc[4 * j + 3]);
      }
    }
  }

  int node = node0 + nl;
  if (node < N) {
    float4* o4 = (float4*)&out[(size_t)node * OUT + og];
#pragma unroll
    for (int j = 0; j < 4; ++j)
      o4[j] = make_float4(acc[4 * j], acc[4 * j + 1], acc[4 * j + 2], acc[4 * j + 3]);
  }
}

extern "C" void kernel_launch(void* const* d_in, const int* in_sizes, int n_in,
                              void* d_out, int out_size, void* d_ws, size_t ws_size,
                              hipStream_t stream) {
  const float* x    = (const float*)d_in[0];
  const int*   erow = (const int*)d_in[1];
  const int*   ecol = (const int*)d_in[2];
  const float* eval = (const float*)d_in[3];
  const float* W    = (const float*)d_in[4];
  const float* b    = (const float*)d_in[5];
  float* out = (float*)d_out;

  int N = in_sizes[0] / F;
  int E = in_sizes[1];
  size_t SZ = (size_t)N * F * sizeof(float);
  int nScanBlocks = (N + SCAN_ELEMS - 1) / SCAN_ELEMS;

  // ws layout (8B-aligned records first)
  char* p = (char*)d_ws;
  float*  hA     = (float*)p;  p += SZ;
  float*  hB     = (float*)p;  p += SZ;
  float2* recs   = (float2*)p; p += (size_t)E * sizeof(float2);
  int*    counts = (int*)p;    p += (size_t)N * sizeof(int);
  int*    offs   = (int*)p;    p += (size_t)(N + 1) * sizeof(int);
  int*    cursor = (int*)p;    p += (size_t)N * sizeof(int);
  int*    bsums  = (int*)p;    p += (size_t)nScanBlocks * sizeof(int);

  int egrid = (E + 255) / 256;
  int sgrid = (N + 3) / 4;
  int ggrid = (N + 63) / 64;

  // --- CSR build ---
  hipMemsetAsync(counts, 0, (size_t)N * sizeof(int), stream);
  count_rows<<<egrid, 256, 0, stream>>>(erow, counts, E);
  block_scan<<<nScanBlocks, 256, 0, stream>>>(counts, offs, bsums, N);
  scan_sums<<<1, 64, 0, stream>>>(bsums, nScanBlocks);
  add_offsets<<<(N + 255) / 256, 256, 0, stream>>>(offs, bsums, cursor, N, E);
  scatter_edges<<<egrid, 256, 0, stream>>>(erow, ecol, eval, cursor, recs, E);

  // --- propagation (h3 goes straight into d_out as scratch) ---
  spmm_rec<<<sgrid, 256, 0, stream>>>(offs, recs, x, hA, N);    // h1
  spmm_rec<<<sgrid, 256, 0, stream>>>(offs, recs, hA, hB, N);   // h2
  spmm_rec<<<sgrid, 256, 0, stream>>>(offs, recs, hB, out, N);  // h3

  // out = b + x@W0 + h1@W1 + h2@W2 + h3@W3 (h3 read from out tile-locally)
  gemm_fused4<<<ggrid, 256, 0, stream>>>(x, hA, hB, W, b, out, N);
}

// Round 5
// 232.918 us; speedup vs baseline: 2.6680x; 1.1660x over previous
//
#include <hip/hip_runtime.h>

// TAGConv: N=50000, E=800000, F=64, OUT=64, K=3.
// Round 5: spmm with float4 group-gather (4 edges per VMEM instr);
// GEMM with register-resident acc, global-L1 h stream, vectorized W fill.

#define F 64
#define OUT 64
#define SCAN_ELEMS 1024

__global__ __launch_bounds__(256) void count_rows(
    const int* __restrict__ row, int* __restrict__ counts, int E) {
  int e = blockIdx.x * 256 + threadIdx.x;
  if (e < E) atomicAdd(&counts[row[e]], 1);
}

__global__ __launch_bounds__(256) void block_scan(
    const int* __restrict__ counts, int* __restrict__ offsets,
    int* __restrict__ blockSums, int N) {
  __shared__ int s[256];
  int t = threadIdx.x;
  int base = blockIdx.x * SCAN_ELEMS + t * 4;
  int v0 = 0, v1 = 0, v2 = 0, v3 = 0;
  if (base + 3 < N) {
    int4 c = *(const int4*)&counts[base];
    v0 = c.x; v1 = c.y; v2 = c.z; v3 = c.w;
  } else {
    if (base < N)     v0 = counts[base];
    if (base + 1 < N) v1 = counts[base + 1];
    if (base + 2 < N) v2 = counts[base + 2];
  }
  s[t] = v0 + v1 + v2 + v3;
  __syncthreads();
  for (int d = 1; d < 256; d <<= 1) {
    int x = (t >= d) ? s[t - d] : 0;
    __syncthreads();
    s[t] += x;
    __syncthreads();
  }
  int ex = (t == 0) ? 0 : s[t - 1];
  if (t == 255) blockSums[blockIdx.x] = s[255];
  int o0 = ex, o1 = o0 + v0, o2 = o1 + v1, o3 = o2 + v2;
  if (base + 3 < N) {
    *(int4*)&offsets[base] = make_int4(o0, o1, o2, o3);
  } else {
    if (base < N)     offsets[base]     = o0;
    if (base + 1 < N) offsets[base + 1] = o1;
    if (base + 2 < N) offsets[base + 2] = o2;
  }
}

__global__ __launch_bounds__(64) void scan_sums(int* __restrict__ blockSums, int nb) {
  int lane = threadIdx.x;
  if (nb <= 64) {
    int v = (lane < nb) ? blockSums[lane] : 0;
    int incl = v;
    for (int d = 1; d < 64; d <<= 1) {
      int u = __shfl_up(incl, d, 64);
      if (lane >= d) incl += u;
    }
    if (lane < nb) blockSums[lane] = incl - v;
  } else if (lane == 0) {
    int run = 0;
    for (int i = 0; i < nb; ++i) { int c = blockSums[i]; blockSums[i] = run; run += c; }
  }
}

__global__ __launch_bounds__(256) void add_offsets(
    int* __restrict__ offsets, const int* __restrict__ blockSums,
    int* __restrict__ cursor, int N, int E) {
  int i = blockIdx.x * 256 + threadIdx.x;
  if (i < N) {
    int o = offsets[i] + blockSums[i >> 10];
    offsets[i] = o;
    cursor[i] = o;
  }
  if (i == 0) offsets[N] = E;
}

__global__ __launch_bounds__(256) void scatter_edges(
    const int* __restrict__ row, const int* __restrict__ col,
    const float* __restrict__ val, int* __restrict__ cursor,
    float2* __restrict__ recs, int E) {
  int e = blockIdx.x * 256 + threadIdx.x;
  if (e < E) {
    int r = row[e];
    int p = atomicAdd(&cursor[r], 1);
    recs[p] = make_float2(__int_as_float(col[e]), val[e]);
  }
}

// Wave per row. 4 groups of 16 lanes; group g handles edges i+g, i+g+4, ...
// Each lane gathers a float4 of features -> 4 edges per b128 VMEM instr.
__global__ __launch_bounds__(256) void spmm_rec4(
    const int* __restrict__ off, const float2* __restrict__ recs,
    const float* __restrict__ hin, float* __restrict__ hout, int N) {
  int r = blockIdx.x * 4 + (threadIdx.x >> 6);
  if (r >= N) return;
  int lane = threadIdx.x & 63;
  int g = lane >> 4;
  int fp = (lane & 15) << 2;
  int i = off[r], end = off[r + 1];
  float4 acc = make_float4(0.f, 0.f, 0.f, 0.f);

  int bb = i + g;
  for (; bb + 4 < end; bb += 8) {
    float2 e0 = recs[bb];
    float2 e1 = recs[bb + 4];
    float4 h0 = *(const float4*)&hin[(size_t)__float_as_int(e0.x) * F + fp];
    float4 h1 = *(const float4*)&hin[(size_t)__float_as_int(e1.x) * F + fp];
    acc.x = fmaf(e0.y, h0.x, acc.x);
    acc.y = fmaf(e0.y, h0.y, acc.y);
    acc.z = fmaf(e0.y, h0.z, acc.z);
    acc.w = fmaf(e0.y, h0.w, acc.w);
    acc.x = fmaf(e1.y, h1.x, acc.x);
    acc.y = fmaf(e1.y, h1.y, acc.y);
    acc.z = fmaf(e1.y, h1.z, acc.z);
    acc.w = fmaf(e1.y, h1.w, acc.w);
  }
  if (bb < end) {
    float2 e0 = recs[bb];
    float4 h0 = *(const float4*)&hin[(size_t)__float_as_int(e0.x) * F + fp];
    acc.x = fmaf(e0.y, h0.x, acc.x);
    acc.y = fmaf(e0.y, h0.y, acc.y);
    acc.z = fmaf(e0.y, h0.z, acc.z);
    acc.w = fmaf(e0.y, h0.w, acc.w);
  }

  // reduce across the 4 groups (lanes differing in bits 4,5)
  acc.x += __shfl_xor(acc.x, 16, 64);
  acc.y += __shfl_xor(acc.y, 16, 64);
  acc.z += __shfl_xor(acc.z, 16, 64);
  acc.w += __shfl_xor(acc.w, 16, 64);
  acc.x += __shfl_xor(acc.x, 32, 64);
  acc.y += __shfl_xor(acc.y, 32, 64);
  acc.z += __shfl_xor(acc.z, 32, 64);
  acc.w += __shfl_xor(acc.w, 32, 64);

  if (g == 0) *(float4*)&hout[(size_t)r * F + fp] = acc;
}

// out = bias + h0@W0 + h1@W1 + h2@W2 + h3@W3 (h3 lives in out).
// Thread = (node, 16 outs). h streamed float4 from global (L1-broadcast for
// the 4 lanes sharing a node); W chunk in LDS, filled with float4 loads.
__global__ __launch_bounds__(256) void gemm_fused4_v2(
    const float* __restrict__ h0, const float* __restrict__ h1,
    const float* __restrict__ h2, const float* __restrict__ W,
    const float* __restrict__ bias, float* __restrict__ out, int N) {
  __shared__ float Ws[64 * 64];
  const float* hs[4] = {h0, h1, h2, out};

  int nl = threadIdx.x >> 2;
  int oq = threadIdx.x & 3;
  int og = oq << 4;
  int node = blockIdx.x * 64 + nl;
  int nodec = min(node, N - 1);

  const float4* b4 = (const float4*)bias;
  float4 a0 = b4[oq * 4 + 0];
  float4 a1 = b4[oq * 4 + 1];
  float4 a2 = b4[oq * 4 + 2];
  float4 a3 = b4[oq * 4 + 3];

  for (int s = 0; s < 4; ++s) {
    __syncthreads();
    const float4* Wg = (const float4*)(W + s * 4096);
#pragma unroll
    for (int i = 0; i < 4; ++i)
      ((float4*)Ws)[threadIdx.x + i * 256] = Wg[threadIdx.x + i * 256];
    __syncthreads();

    const float* hrow = hs[s] + (size_t)nodec * F;
#pragma unroll 4
    for (int k4 = 0; k4 < 16; ++k4) {
      float4 h4 = *(const float4*)&hrow[k4 * 4];
#pragma unroll
      for (int j = 0; j < 4; ++j) {
        float hv = (j == 0) ? h4.x : (j == 1) ? h4.y : (j == 2) ? h4.z : h4.w;
        const float4* w4 = (const float4*)&Ws[(k4 * 4 + j) * 64 + og];
        float4 w0 = w4[0], w1 = w4[1], w2 = w4[2], w3 = w4[3];
        a0.x = fmaf(hv, w0.x, a0.x); a0.y = fmaf(hv, w0.y, a0.y);
        a0.z = fmaf(hv, w0.z, a0.z); a0.w = fmaf(hv, w0.w, a0.w);
        a1.x = fmaf(hv, w1.x, a1.x); a1.y = fmaf(hv, w1.y, a1.y);
        a1.z = fmaf(hv, w1.z, a1.z); a1.w = fmaf(hv, w1.w, a1.w);
        a2.x = fmaf(hv, w2.x, a2.x); a2.y = fmaf(hv, w2.y, a2.y);
        a2.z = fmaf(hv, w2.z, a2.z); a2.w = fmaf(hv, w2.w, a2.w);
        a3.x = fmaf(hv, w3.x, a3.x); a3.y = fmaf(hv, w3.y, a3.y);
        a3.z = fmaf(hv, w3.z, a3.z); a3.w = fmaf(hv, w3.w, a3.w);
      }
    }
  }

  if (node < N) {
    float4* o4 = (float4*)&out[(size_t)node * OUT + og];
    o4[0] = a0; o4[1] = a1; o4[2] = a2; o4[3] = a3;
  }
}

extern "C" void kernel_launch(void* const* d_in, const int* in_sizes, int n_in,
                              void* d_out, int out_size, void* d_ws, size_t ws_size,
                              hipStream_t stream) {
  const float* x    = (const float*)d_in[0];
  const int*   erow = (const int*)d_in[1];
  const int*   ecol = (const int*)d_in[2];
  const float* eval = (const float*)d_in[3];
  const float* W    = (const float*)d_in[4];
  const float* b    = (const float*)d_in[5];
  float* out = (float*)d_out;

  int N = in_sizes[0] / F;
  int E = in_sizes[1];
  size_t SZ = (size_t)N * F * sizeof(float);
  int nScanBlocks = (N + SCAN_ELEMS - 1) / SCAN_ELEMS;

  char* p = (char*)d_ws;
  float*  hA     = (float*)p;  p += SZ;
  float*  hB     = (float*)p;  p += SZ;
  float2* recs   = (float2*)p; p += (size_t)E * sizeof(float2);
  int*    counts = (int*)p;    p += (size_t)N * sizeof(int);
  int*    offs   = (int*)p;    p += (size_t)(N + 1) * sizeof(int);
  int*    cursor = (int*)p;    p += (size_t)N * sizeof(int);
  int*    bsums  = (int*)p;    p += (size_t)nScanBlocks * sizeof(int);

  int egrid = (E + 255) / 256;
  int sgrid = (N + 3) / 4;
  int ggrid = (N + 63) / 64;

  // --- CSR build ---
  hipMemsetAsync(counts, 0, (size_t)N * sizeof(int), stream);
  count_rows<<<egrid, 256, 0, stream>>>(erow, counts, E);
  block_scan<<<nScanBlocks, 256, 0, stream>>>(counts, offs, bsums, N);
  scan_sums<<<1, 64, 0, stream>>>(bsums, nScanBlocks);
  add_offsets<<<(N + 255) / 256, 256, 0, stream>>>(offs, bsums, cursor, N, E);
  scatter_edges<<<egrid, 256, 0, stream>>>(erow, ecol, eval, cursor, recs, E);

  // --- propagation (h3 -> d_out as scratch) ---
  spmm_rec4<<<sgrid, 256, 0, stream>>>(offs, recs, x, hA, N);    // h1
  spmm_rec4<<<sgrid, 256, 0, stream>>>(offs, recs, hA, hB, N);   // h2
  spmm_rec4<<<sgrid, 256, 0, stream>>>(offs, recs, hB, out, N);  // h3

  gemm_fused4_v2<<<ggrid, 256, 0, stream>>>(x, hA, hB, W, b, out, N);
}

// Round 6
// 217.841 us; speedup vs baseline: 2.8527x; 1.0692x over previous
//
#include <hip/hip_runtime.h>

// TAGConv: N=50000, E=800000, F=64, OUT=64, K=3.
// Round 6: XCD-partitioned scatter (writes stay in one XCD's L2 -> ~1x write
// amp) + spmm with 16-lane group per row (fewer iters, no reduce).

#define F 64
#define OUT 64
#define SCAN_ELEMS 1024
#define NPART 8

__global__ __launch_bounds__(256) void count_rows(
    const int* __restrict__ row, int* __restrict__ counts, int E) {
  int e = blockIdx.x * 256 + threadIdx.x;
  if (e < E) atomicAdd(&counts[row[e]], 1);
}

__global__ __launch_bounds__(256) void block_scan(
    const int* __restrict__ counts, int* __restrict__ offsets,
    int* __restrict__ blockSums, int N) {
  __shared__ int s[256];
  int t = threadIdx.x;
  int base = blockIdx.x * SCAN_ELEMS + t * 4;
  int v0 = 0, v1 = 0, v2 = 0, v3 = 0;
  if (base + 3 < N) {
    int4 c = *(const int4*)&counts[base];
    v0 = c.x; v1 = c.y; v2 = c.z; v3 = c.w;
  } else {
    if (base < N)     v0 = counts[base];
    if (base + 1 < N) v1 = counts[base + 1];
    if (base + 2 < N) v2 = counts[base + 2];
  }
  s[t] = v0 + v1 + v2 + v3;
  __syncthreads();
  for (int d = 1; d < 256; d <<= 1) {
    int x = (t >= d) ? s[t - d] : 0;
    __syncthreads();
    s[t] += x;
    __syncthreads();
  }
  int ex = (t == 0) ? 0 : s[t - 1];
  if (t == 255) blockSums[blockIdx.x] = s[255];
  int o0 = ex, o1 = o0 + v0, o2 = o1 + v1, o3 = o2 + v2;
  if (base + 3 < N) {
    *(int4*)&offsets[base] = make_int4(o0, o1, o2, o3);
  } else {
    if (base < N)     offsets[base]     = o0;
    if (base + 1 < N) offsets[base + 1] = o1;
    if (base + 2 < N) offsets[base + 2] = o2;
  }
}

__global__ __launch_bounds__(64) void scan_sums(int* __restrict__ blockSums, int nb) {
  int lane = threadIdx.x;
  if (nb <= 64) {
    int v = (lane < nb) ? blockSums[lane] : 0;
    int incl = v;
    for (int d = 1; d < 64; d <<= 1) {
      int u = __shfl_up(incl, d, 64);
      if (lane >= d) incl += u;
    }
    if (lane < nb) blockSums[lane] = incl - v;
  } else if (lane == 0) {
    int run = 0;
    for (int i = 0; i < nb; ++i) { int c = blockSums[i]; blockSums[i] = run; run += c; }
  }
}

__global__ __launch_bounds__(256) void add_offsets(
    int* __restrict__ offsets, const int* __restrict__ blockSums,
    int* __restrict__ cursor, int N, int E) {
  int i = blockIdx.x * 256 + threadIdx.x;
  if (i < N) {
    int o = offsets[i] + blockSums[i >> 10];
    offsets[i] = o;
    cursor[i] = o;
  }
  if (i == 0) offsets[N] = E;
}

// XCD-partitioned scatter: block (chunk = bid>>3, part = bid&7). Only edges
// whose row falls in this partition's contiguous row range are written, so
// each recs line is written by one XCD's L2 (dispatch round-robins bid%8
// across XCDs). Every edge passes exactly one partition filter -> correct
// under any block->XCD mapping.
__global__ __launch_bounds__(256) void scatter_part(
    const int* __restrict__ row, const int* __restrict__ col,
    const float* __restrict__ val, int* __restrict__ cursor,
    float2* __restrict__ recs, int E, int rpp) {
  int part = blockIdx.x & (NPART - 1);
  int e = (blockIdx.x >> 3) * 256 + threadIdx.x;
  if (e >= E) return;
  int r = row[e];
  unsigned lo = (unsigned)(part * rpp);
  if ((unsigned)(r - lo) >= (unsigned)rpp) return;
  int p = atomicAdd(&cursor[r], 1);
  recs[p] = make_float2(__int_as_float(col[e]), val[e]);
}

// 16-lane group per row; lane owns 4 features. Serial edge loop, 4-unrolled
// (4 independent b128 gathers in flight per group). No cross-lane reduce.
__global__ __launch_bounds__(256) void spmm_g16(
    const int* __restrict__ off, const float2* __restrict__ recs,
    const float* __restrict__ hin, float* __restrict__ hout, int N) {
  int r = (blockIdx.x * 256 + threadIdx.x) >> 4;
  if (r >= N) return;
  int fp = (threadIdx.x & 15) << 2;
  int i = off[r], end = off[r + 1];
  float4 acc = make_float4(0.f, 0.f, 0.f, 0.f);

  for (; i + 4 <= end; i += 4) {
    float2 e0 = recs[i], e1 = recs[i + 1], e2 = recs[i + 2], e3 = recs[i + 3];
    float4 h0 = *(const float4*)&hin[(size_t)__float_as_int(e0.x) * F + fp];
    float4 h1 = *(const float4*)&hin[(size_t)__float_as_int(e1.x) * F + fp];
    float4 h2 = *(const float4*)&hin[(size_t)__float_as_int(e2.x) * F + fp];
    float4 h3 = *(const float4*)&hin[(size_t)__float_as_int(e3.x) * F + fp];
    acc.x = fmaf(e0.y, h0.x, acc.x); acc.y = fmaf(e0.y, h0.y, acc.y);
    acc.z = fmaf(e0.y, h0.z, acc.z); acc.w = fmaf(e0.y, h0.w, acc.w);
    acc.x = fmaf(e1.y, h1.x, acc.x); acc.y = fmaf(e1.y, h1.y, acc.y);
    acc.z = fmaf(e1.y, h1.z, acc.z); acc.w = fmaf(e1.y, h1.w, acc.w);
    acc.x = fmaf(e2.y, h2.x, acc.x); acc.y = fmaf(e2.y, h2.y, acc.y);
    acc.z = fmaf(e2.y, h2.z, acc.z); acc.w = fmaf(e2.y, h2.w, acc.w);
    acc.x = fmaf(e3.y, h3.x, acc.x); acc.y = fmaf(e3.y, h3.y, acc.y);
    acc.z = fmaf(e3.y, h3.z, acc.z); acc.w = fmaf(e3.y, h3.w, acc.w);
  }
  for (; i < end; ++i) {
    float2 e0 = recs[i];
    float4 h0 = *(const float4*)&hin[(size_t)__float_as_int(e0.x) * F + fp];
    acc.x = fmaf(e0.y, h0.x, acc.x); acc.y = fmaf(e0.y, h0.y, acc.y);
    acc.z = fmaf(e0.y, h0.z, acc.z); acc.w = fmaf(e0.y, h0.w, acc.w);
  }
  *(float4*)&hout[(size_t)r * F + fp] = acc;
}

// out = bias + h0@W0 + h1@W1 + h2@W2 + h3@W3 (h3 lives in out).
__global__ __launch_bounds__(256) void gemm_fused4_v2(
    const float* __restrict__ h0, const float* __restrict__ h1,
    const float* __restrict__ h2, const float* __restrict__ W,
    const float* __restrict__ bias, float* __restrict__ out, int N) {
  __shared__ float Ws[64 * 64];
  const float* hs[4] = {h0, h1, h2, out};

  int nl = threadIdx.x >> 2;
  int oq = threadIdx.x & 3;
  int og = oq << 4;
  int node = blockIdx.x * 64 + nl;
  int nodec = min(node, N - 1);

  const float4* b4 = (const float4*)bias;
  float4 a0 = b4[oq * 4 + 0];
  float4 a1 = b4[oq * 4 + 1];
  float4 a2 = b4[oq * 4 + 2];
  float4 a3 = b4[oq * 4 + 3];

  for (int s = 0; s < 4; ++s) {
    __syncthreads();
    const float4* Wg = (const float4*)(W + s * 4096);
#pragma unroll
    for (int i = 0; i < 4; ++i)
      ((float4*)Ws)[threadIdx.x + i * 256] = Wg[threadIdx.x + i * 256];
    __syncthreads();

    const float* hrow = hs[s] + (size_t)nodec * F;
#pragma unroll 4
    for (int k4 = 0; k4 < 16; ++k4) {
      float4 h4 = *(const float4*)&hrow[k4 * 4];
#pragma unroll
      for (int j = 0; j < 4; ++j) {
        float hv = (j == 0) ? h4.x : (j == 1) ? h4.y : (j == 2) ? h4.z : h4.w;
        const float4* w4 = (const float4*)&Ws[(k4 * 4 + j) * 64 + og];
        float4 w0 = w4[0], w1 = w4[1], w2 = w4[2], w3 = w4[3];
        a0.x = fmaf(hv, w0.x, a0.x); a0.y = fmaf(hv, w0.y, a0.y);
        a0.z = fmaf(hv, w0.z, a0.z); a0.w = fmaf(hv, w0.w, a0.w);
        a1.x = fmaf(hv, w1.x, a1.x); a1.y = fmaf(hv, w1.y, a1.y);
        a1.z = fmaf(hv, w1.z, a1.z); a1.w = fmaf(hv, w1.w, a1.w);
        a2.x = fmaf(hv, w2.x, a2.x); a2.y = fmaf(hv, w2.y, a2.y);
        a2.z = fmaf(hv, w2.z, a2.z); a2.w = fmaf(hv, w2.w, a2.w);
        a3.x = fmaf(hv, w3.x, a3.x); a3.y = fmaf(hv, w3.y, a3.y);
        a3.z = fmaf(hv, w3.z, a3.z); a3.w = fmaf(hv, w3.w, a3.w);
      }
    }
  }

  if (node < N) {
    float4* o4 = (float4*)&out[(size_t)node * OUT + og];
    o4[0] = a0; o4[1] = a1; o4[2] = a2; o4[3] = a3;
  }
}

extern "C" void kernel_launch(void* const* d_in, const int* in_sizes, int n_in,
                              void* d_out, int out_size, void* d_ws, size_t ws_size,
                              hipStream_t stream) {
  const float* x    = (const float*)d_in[0];
  const int*   erow = (const int*)d_in[1];
  const int*   ecol = (const int*)d_in[2];
  const float* eval = (const float*)d_in[3];
  const float* W    = (const float*)d_in[4];
  const float* b    = (const float*)d_in[5];
  float* out = (float*)d_out;

  int N = in_sizes[0] / F;
  int E = in_sizes[1];
  size_t SZ = (size_t)N * F * sizeof(float);
  int nScanBlocks = (N + SCAN_ELEMS - 1) / SCAN_ELEMS;
  int rpp = (N + NPART - 1) / NPART;

  char* p = (char*)d_ws;
  float*  hA     = (float*)p;  p += SZ;
  float*  hB     = (float*)p;  p += SZ;
  float2* recs   = (float2*)p; p += (size_t)E * sizeof(float2);
  int*    counts = (int*)p;    p += (size_t)N * sizeof(int);
  int*    offs   = (int*)p;    p += (size_t)(N + 1) * sizeof(int);
  int*    cursor = (int*)p;    p += (size_t)N * sizeof(int);
  int*    bsums  = (int*)p;    p += (size_t)nScanBlocks * sizeof(int);

  int egrid = (E + 255) / 256;
  int g16grid = ((size_t)N * 16 + 255) / 256;
  int ggrid = (N + 63) / 64;

  // --- CSR build ---
  hipMemsetAsync(counts, 0, (size_t)N * sizeof(int), stream);
  count_rows<<<egrid, 256, 0, stream>>>(erow, counts, E);
  block_scan<<<nScanBlocks, 256, 0, stream>>>(counts, offs, bsums, N);
  scan_sums<<<1, 64, 0, stream>>>(bsums, nScanBlocks);
  add_offsets<<<(N + 255) / 256, 256, 0, stream>>>(offs, bsums, cursor, N, E);
  scatter_part<<<egrid * NPART, 256, 0, stream>>>(erow, ecol, eval, cursor, recs, E, rpp);

  // --- propagation (h3 -> d_out as scratch) ---
  spmm_g16<<<g16grid, 256, 0, stream>>>(offs, recs, x, hA, N);    // h1
  spmm_g16<<<g16grid, 256, 0, stream>>>(offs, recs, hA, hB, N);   // h2
  spmm_g16<<<g16grid, 256, 0, stream>>>(offs, recs, hB, out, N);  // h3

  gemm_fused4_v2<<<ggrid, 256, 0, stream>>>(x, hA, hB, W, b, out, N);
}